// Round 1
// baseline (555.857 us; speedup 1.0000x reference)
//
#include <hip/hip_runtime.h>

typedef unsigned short u16;
typedef unsigned int u32;
typedef short v8s __attribute__((ext_vector_type(8)));
typedef float v4f __attribute__((ext_vector_type(4)));

#define MFMA16(a, b, c) __builtin_amdgcn_mfma_f32_16x16x32_bf16(a, b, c, 0, 0, 0)

__device__ __forceinline__ u16 f2bf(float f) {
  u32 u = __float_as_uint(f);
  u32 r = (u + 0x7fffu + ((u >> 16) & 1u)) >> 16;
  return (u16)r;
}
__device__ __forceinline__ float bf2f(u16 s) {
  return __uint_as_float(((u32)s) << 16);
}

// ---------------------------------------------------------------------------
// generic f32 -> bf16 convert
__global__ __launch_bounds__(256) void cvt_bf(const float* __restrict__ in,
                                              u16* __restrict__ out, int n) {
  for (int i = blockIdx.x * 256 + threadIdx.x; i < n; i += gridDim.x * 256)
    out[i] = f2bf(in[i]);
}

// ---------------------------------------------------------------------------
// fused depthwise conv 3x3 + 5x5 + 7x7 (stride 1, same padding), one WG per (b,c)
__global__ __launch_bounds__(256) void conv_kernel(
    const float* __restrict__ y, const float* __restrict__ w1, const float* __restrict__ b1,
    const float* __restrict__ w2, const float* __restrict__ b2,
    const float* __restrict__ w3, const float* __restrict__ b3, float* __restrict__ yf) {
  __shared__ float img[38 * 40];
  __shared__ float wl[84];
  int blk = blockIdx.x;           // b*512 + c
  int c = blk & 511;
  int t = threadIdx.x;
  const float* ybase = &y[(size_t)blk * 1024];
  for (int idx = t; idx < 38 * 40; idx += 256) {
    int row = idx / 40, col = idx - row * 40;
    float v = 0.f;
    int gh = row - 3, gw = col - 3;
    if (col < 38 && gh >= 0 && gh < 32 && gw >= 0 && gw < 32) v = ybase[gh * 32 + gw];
    if (col < 38) img[idx] = v;
  }
  if (t < 49) wl[t] = w3[c * 49 + t];
  else if (t < 74) wl[t] = w2[c * 25 + (t - 49)];
  else if (t < 83) wl[t] = w1[c * 9 + (t - 74)];
  float bias = b1[c] + b2[c] + b3[c];
  __syncthreads();
  for (int p = t; p < 1024; p += 256) {
    int hh = p >> 5, ww = p & 31;
    float acc = bias;
#pragma unroll
    for (int i = 0; i < 7; i++)
#pragma unroll
      for (int j = 0; j < 7; j++)
        acc += img[(hh + i) * 40 + ww + j] * wl[i * 7 + j];
#pragma unroll
    for (int i = 0; i < 5; i++)
#pragma unroll
      for (int j = 0; j < 5; j++)
        acc += img[(hh + 1 + i) * 40 + ww + 1 + j] * wl[49 + i * 5 + j];
#pragma unroll
    for (int i = 0; i < 3; i++)
#pragma unroll
      for (int j = 0; j < 3; j++)
        acc += img[(hh + 2 + i) * 40 + ww + 2 + j] * wl[74 + i * 3 + j];
    yf[(size_t)blk * 1024 + p] = acc;
  }
}

// ---------------------------------------------------------------------------
// LayerNorm over C=512 for 16 pixels per WG; yf [B,C,N] f32 -> yn [B*N, C] bf16
__global__ __launch_bounds__(256) void ln_kernel(const float* __restrict__ yf,
                                                 const float* __restrict__ lnw,
                                                 const float* __restrict__ lnb,
                                                 u16* __restrict__ ynbf) {
  __shared__ float T[512][17];
  __shared__ float ps1[16][16], ps2[16][16];
  __shared__ float mu_s[16], rs_s[16];
  int blk = blockIdx.x;  // b*64 + n-group
  int b = blk >> 6;
  int n0 = (blk & 63) << 4;
  int t = threadIdx.x;
  for (int idx = t; idx < 8192; idx += 256) {
    int c = idx >> 4, j = idx & 15;
    T[c][j] = yf[((size_t)(b * 512 + c)) * 1024 + n0 + j];
  }
  __syncthreads();
  {
    int j = t & 15, part = t >> 4;
    float s1 = 0.f, s2 = 0.f;
#pragma unroll 4
    for (int cc = 0; cc < 32; cc++) {
      float v = T[part * 32 + cc][j];
      s1 += v;
      s2 += v * v;
    }
    ps1[part][j] = s1;
    ps2[part][j] = s2;
  }
  __syncthreads();
  if (t < 16) {
    float a1 = 0.f, a2 = 0.f;
#pragma unroll
    for (int p = 0; p < 16; p++) { a1 += ps1[p][t]; a2 += ps2[p][t]; }
    float mu = a1 * (1.f / 512.f);
    float var = a2 * (1.f / 512.f) - mu * mu;
    mu_s[t] = mu;
    rs_s[t] = rsqrtf(var + 1e-5f);
  }
  __syncthreads();
  for (int idx = t; idx < 8192; idx += 256) {
    int c = idx & 511, jj = idx >> 9;
    float v = (T[c][jj] - mu_s[jj]) * rs_s[jj] * lnw[c] + lnb[c];
    ynbf[((size_t)(b * 1024 + n0 + jj)) * 512 + c] = f2bf(v);
  }
}

// ---------------------------------------------------------------------------
// x [B,C,N] f32 -> xs [B*N, C] bf16 (transpose + convert)
__global__ __launch_bounds__(256) void xpose_x(const float* __restrict__ x,
                                               u16* __restrict__ xsbf) {
  __shared__ float T[32][33];
  int blk = blockIdx.x;  // ((b*16 + cb)*32 + nb)
  int nb = blk & 31, cb = (blk >> 5) & 15, b = blk >> 9;
  int c0 = cb * 32, n0 = nb * 32;
  int t = threadIdx.x;
  for (int idx = t; idx < 1024; idx += 256) {
    int ci = idx >> 5, nj = idx & 31;
    T[ci][nj] = x[((size_t)(b * 512 + c0 + ci)) * 1024 + n0 + nj];
  }
  __syncthreads();
  for (int idx = t; idx < 1024; idx += 256) {
    int nj = idx >> 5, ci = idx & 31;
    xsbf[((size_t)(b * 1024 + n0 + nj)) * 512 + c0 + ci] = f2bf(T[ci][nj]);
  }
}

// ---------------------------------------------------------------------------
// v half of kv [B*N, 1024] bf16 -> vT [B,H,64,1024] bf16
__global__ __launch_bounds__(256) void xpose_v(const u16* __restrict__ kvbf,
                                               u16* __restrict__ vT) {
  __shared__ u16 T[64][72];
  int blk = blockIdx.x;  // (b*8+h)*16 + nt
  int nt = blk & 15, bh = blk >> 4;
  int b = bh >> 3, h = bh & 7;
  int n0 = nt * 64;
  int t = threadIdx.x;
  for (int idx = t; idx < 4096; idx += 256) {
    int ni = idx >> 6, dj = idx & 63;
    T[ni][dj] = kvbf[((size_t)(b * 1024 + n0 + ni)) * 1024 + 512 + h * 64 + dj];
  }
  __syncthreads();
  for (int idx = t; idx < 4096; idx += 256) {
    int dj = idx >> 6, ni = idx & 63;
    vT[((size_t)(bh * 64 + dj)) * 1024 + n0 + ni] = T[ni][dj];
  }
}

// ---------------------------------------------------------------------------
// bf16 NT GEMM: C[M,N] = A[M,K] * B[N,K]^T ; out f32 or bf16
__global__ __launch_bounds__(256) void gemm_nt(const u16* __restrict__ A,
                                               const u16* __restrict__ B, void* __restrict__ Cout,
                                               int M, int N, int K, int outBF) {
  __shared__ u16 As[128 * 40];
  __shared__ u16 Bs[128 * 40];
  int blk = blockIdx.x;
  int nblk = N >> 7;
  int m0 = (blk / nblk) << 7, n0 = (blk % nblk) << 7;
  int t = threadIdx.x;
  int lane = t & 63, w = t >> 6;
  int wr = w >> 1, wc = w & 1;
  int lr = lane & 15, kr = lane >> 4;

  v4f acc[4][4];
#pragma unroll
  for (int i = 0; i < 4; i++)
#pragma unroll
    for (int j = 0; j < 4; j++) acc[i][j] = (v4f){0.f, 0.f, 0.f, 0.f};

  const int r0 = t >> 2, s0 = (t & 3) * 8;
  const int r1 = r0 + 64;

  for (int k0 = 0; k0 < K; k0 += 32) {
    int4 a0 = *(const int4*)&A[(size_t)(m0 + r0) * K + k0 + s0];
    int4 a1 = *(const int4*)&A[(size_t)(m0 + r1) * K + k0 + s0];
    int4 b0 = *(const int4*)&B[(size_t)(n0 + r0) * K + k0 + s0];
    int4 b1 = *(const int4*)&B[(size_t)(n0 + r1) * K + k0 + s0];
    __syncthreads();
    *(int4*)&As[r0 * 40 + s0] = a0;
    *(int4*)&As[r1 * 40 + s0] = a1;
    *(int4*)&Bs[r0 * 40 + s0] = b0;
    *(int4*)&Bs[r1 * 40 + s0] = b1;
    __syncthreads();
    v8s af[4], bfr[4];
#pragma unroll
    for (int i = 0; i < 4; i++) af[i] = *(const v8s*)&As[(wr * 64 + i * 16 + lr) * 40 + kr * 8];
#pragma unroll
    for (int i = 0; i < 4; i++) bfr[i] = *(const v8s*)&Bs[(wc * 64 + i * 16 + lr) * 40 + kr * 8];
#pragma unroll
    for (int i = 0; i < 4; i++)
#pragma unroll
      for (int j = 0; j < 4; j++) acc[i][j] = MFMA16(af[i], bfr[j], acc[i][j]);
  }
#pragma unroll
  for (int i = 0; i < 4; i++)
#pragma unroll
    for (int j = 0; j < 4; j++) {
      int row = m0 + wr * 64 + i * 16 + kr * 4;
      int col = n0 + wc * 64 + j * 16 + lr;
#pragma unroll
      for (int q = 0; q < 4; q++) {
        float v = acc[i][j][q];
        if (outBF) ((u16*)Cout)[(size_t)(row + q) * N + col] = f2bf(v);
        else ((float*)Cout)[(size_t)(row + q) * N + col] = v;
      }
    }
}

// ---------------------------------------------------------------------------
// fused attention: per WG = (b, h, 16 q-rows). S=qK^T/8 (bf16 LDS), exact
// radix-select top-k thresholds (k1,k2), combined masked softmax weights,
// PV via MFMA, bf16 out [B*N, C].
__global__ __launch_bounds__(256) void attn_kernel(
    const u16* __restrict__ qbf, const u16* __restrict__ kvbf, const u16* __restrict__ vT,
    u16* __restrict__ aobf, const float* __restrict__ kr1p, const float* __restrict__ kr2p) {
  __shared__ u16 Sb[16][1032];
  __shared__ u32 hist[16][256];
  __shared__ float opart[4][16][64];
  __shared__ u16 qtile[16][64];

  int blk = blockIdx.x;
  int bh = blk >> 6, rb = blk & 63;
  int b = bh >> 3, h = bh & 7;
  int n0 = rb * 16;
  int t = threadIdx.x, lane = t & 63, w = t >> 6;
  int lr = lane & 15, kr = lane >> 4;

  float sg1 = 1.f / (1.f + __expf(-kr1p[0]));
  int k1 = min(max((int)(1024.f * sg1), 1), 1024);
  float sg2 = 1.f / (1.f + __expf(-kr2p[0]));
  int k2 = min(max((int)(1024.f * sg2), 1), 1024);

  {  // load q tile [16][64]
    int r = t >> 4, seg = t & 15;
    *(uint2*)&qtile[r][seg * 4] =
        *(const uint2*)&qbf[(size_t)(b * 1024 + n0 + r) * 512 + h * 64 + seg * 4];
  }
  __syncthreads();

  {  // Phase 1: S = q K^T * 0.125 -> bf16 LDS
    v8s a0 = *(const v8s*)&qtile[lr][kr * 8];
    v8s a1 = *(const v8s*)&qtile[lr][32 + kr * 8];
    int cbase = w * 256;
#pragma unroll
    for (int cf = 0; cf < 16; cf++) {
      int c0 = cbase + cf * 16;
      const u16* kp = &kvbf[(size_t)(b * 1024 + c0 + lr) * 1024 + h * 64];
      v8s b0 = *(const v8s*)&kp[kr * 8];
      v8s b1 = *(const v8s*)&kp[32 + kr * 8];
      v4f acc = (v4f){0.f, 0.f, 0.f, 0.f};
      acc = MFMA16(a0, b0, acc);
      acc = MFMA16(a1, b1, acc);
#pragma unroll
      for (int j = 0; j < 4; j++) Sb[kr * 4 + j][c0 + lr] = f2bf(acc[j] * 0.125f);
    }
  }
  __syncthreads();

  {  // Phase 2: per-row top-k thresholds + softmax weights (in-place)
    int r = t >> 4, li = t & 15;
    int gb = lane & ~15;

    auto key_at = [&](int e) -> u32 {
      u16 s = Sb[r][li + e * 16];
      return (s & 0x8000u) ? (u32)(u16)(~s) : (u32)(s | 0x8000u);
    };
    auto unkey = [&](u32 kk) -> float {
      u16 s = (kk & 0x8000u) ? (u16)(kk & 0x7fffu) : (u16)(~kk);
      return bf2f(s);
    };

    u32 mx = 0;
    for (int e = 0; e < 64; e++) mx = max(mx, key_at(e));
#pragma unroll
    for (int d = 1; d < 16; d <<= 1) {
      u32 o = __shfl_xor(mx, d, 16);
      mx = max(mx, o);
    }
    float mf = unkey(mx);

    auto build_hist = [&](int pass, u32 prefbyte) {
#pragma unroll
      for (int j = 0; j < 16; j++) hist[r][li * 16 + j] = 0;
      for (int e = 0; e < 64; e++) {
        u32 kk = key_at(e);
        if (pass == 1) atomicAdd(&hist[r][kk >> 8], 1u);
        else if ((kk >> 8) == prefbyte) atomicAdd(&hist[r][kk & 255u], 1u);
      }
    };
    auto find_byte = [&](u32 kk) -> uint2 {
      u32 ci = 0;
#pragma unroll
      for (int j = 0; j < 16; j++) ci += hist[r][li * 16 + j];
      u32 suf = ci;
#pragma unroll
      for (int d = 1; d < 16; d <<= 1) {
        u32 o = __shfl_down(suf, d, 16);
        if (li + d < 16) suf += o;
      }
      u32 tmp = __shfl_down(suf, 1, 16);
      u32 sufn = (li == 15) ? 0u : tmp;
      bool flag = (suf >= kk) && (sufn < kk);
      unsigned long long bal = __ballot(flag);
      int istar = (int)__ffsll((bal >> gb) & 0xffffULL) - 1;
      u32 Sstar1 = __shfl(sufn, istar, 16);
      u32 T = hist[r][istar * 16 + li];
#pragma unroll
      for (int d = 1; d < 16; d <<= 1) {
        u32 o = __shfl_down(T, d, 16);
        if (li + d < 16) T += o;
      }
      u32 tmp2 = __shfl_down(T, 1, 16);
      u32 Tn = (li == 15) ? 0u : tmp2;
      u32 cge = Sstar1 + T, cgen = Sstar1 + Tn;
      bool f2 = (cge >= kk) && (cgen < kk);
      unsigned long long bal2 = __ballot(f2);
      int jstar = (int)__ffsll((bal2 >> gb) & 0xffffULL) - 1;
      u32 newkk = kk - __shfl(cgen, jstar, 16);
      return make_uint2((u32)(istar * 16 + jstar), newkk);
    };

    build_hist(1, 0);
    uint2 p1 = find_byte((u32)k1);
    uint2 p2 = find_byte((u32)k2);
    build_hist(0, p1.x);
    uint2 f1 = find_byte(p1.y);
    u32 t1u = (p1.x << 8) | f1.x;
    build_hist(0, p2.x);
    uint2 f2v = find_byte(p2.y);
    u32 t2u = (p2.x << 8) | f2v.x;

    float z1 = 0.f, z2 = 0.f;
    for (int e = 0; e < 64; e++) {
      u32 kk = key_at(e);
      float ev = __expf(unkey(kk) - mf);
      if (kk >= t1u) z1 += ev;
      if (kk >= t2u) z2 += ev;
    }
#pragma unroll
    for (int d = 1; d < 16; d <<= 1) {
      z1 += __shfl_xor(z1, d, 16);
      z2 += __shfl_xor(z2, d, 16);
    }
    float c1 = 0.6f / z1, c2 = 0.4f / z2;
    for (int e = 0; e < 64; e++) {
      u32 kk = key_at(e);
      float wv = 0.f;
      if (kk >= t1u) {
        float ev = __expf(unkey(kk) - mf);
        wv = ev * (c1 + (kk >= t2u ? c2 : 0.f));
      }
      Sb[r][li + e * 16] = f2bf(wv);
    }
  }
  __syncthreads();

  {  // Phase 3: PV, wave w covers context slice [w*256, w*256+256)
    v4f acc[4];
#pragma unroll
    for (int nf = 0; nf < 4; nf++) acc[nf] = (v4f){0.f, 0.f, 0.f, 0.f};
    int cw = w * 256;
    const u16* vbase = &vT[(size_t)(bh * 64) * 1024];
#pragma unroll
    for (int ks = 0; ks < 8; ks++) {
      int c0 = cw + ks * 32;
      v8s a = *(const v8s*)&Sb[lr][c0 + kr * 8];
#pragma unroll
      for (int nf = 0; nf < 4; nf++) {
        v8s bb = *(const v8s*)&vbase[(size_t)(nf * 16 + lr) * 1024 + c0 + kr * 8];
        acc[nf] = MFMA16(a, bb, acc[nf]);
      }
    }
#pragma unroll
    for (int nf = 0; nf < 4; nf++)
#pragma unroll
      for (int j = 0; j < 4; j++) opart[w][kr * 4 + j][nf * 16 + lr] = acc[nf][j];
  }
  __syncthreads();
  {
    int rr = t >> 4, d0 = (t & 15) * 4;
#pragma unroll
    for (int q = 0; q < 4; q++) {
      float v = opart[0][rr][d0 + q] + opart[1][rr][d0 + q] + opart[2][rr][d0 + q] +
                opart[3][rr][d0 + q];
      aobf[(size_t)(b * 1024 + n0 + rr) * 512 + h * 64 + d0 + q] = f2bf(v);
    }
  }
}

// ---------------------------------------------------------------------------
// final: out[b,c,n] = proj_gemm[(b,n),c] + proj_b[c] + x[b,c,n]
__global__ __launch_bounds__(256) void xpose_out(const float* __restrict__ G,
                                                 const float* __restrict__ x,
                                                 const float* __restrict__ pb,
                                                 float* __restrict__ out) {
  __shared__ float T[32][33];
  int blk = blockIdx.x;  // ((b*16 + cb)*32 + nb)
  int nb = blk & 31, cb = (blk >> 5) & 15, b = blk >> 9;
  int c0 = cb * 32, n0 = nb * 32;
  int t = threadIdx.x;
  for (int idx = t; idx < 1024; idx += 256) {
    int nj = idx >> 5, ci = idx & 31;
    T[ci][nj] = G[((size_t)(b * 1024 + n0 + nj)) * 512 + c0 + ci];
  }
  __syncthreads();
  for (int idx = t; idx < 1024; idx += 256) {
    int ci = idx >> 5, nj = idx & 31;
    size_t o = ((size_t)(b * 512 + c0 + ci)) * 1024 + n0 + nj;
    out[o] = T[ci][nj] + pb[c0 + ci] + x[o];
  }
}

// ---------------------------------------------------------------------------
extern "C" void kernel_launch(void* const* d_in, const int* in_sizes, int n_in,
                              void* d_out, int out_size, void* d_ws, size_t ws_size,
                              hipStream_t stream) {
  (void)in_sizes; (void)n_in; (void)out_size; (void)ws_size;
  const float* x = (const float*)d_in[0];
  const float* y = (const float*)d_in[1];
  const float* q_w = (const float*)d_in[2];
  const float* kv_w = (const float*)d_in[3];
  const float* proj_w = (const float*)d_in[4];
  const float* proj_b = (const float*)d_in[5];
  const float* c1w = (const float*)d_in[6];
  const float* c1b = (const float*)d_in[7];
  const float* c2w = (const float*)d_in[8];
  const float* c2b = (const float*)d_in[9];
  const float* c3w = (const float*)d_in[10];
  const float* c3b = (const float*)d_in[11];
  const float* ln_w = (const float*)d_in[12];
  const float* ln_b = (const float*)d_in[13];
  const float* kr1 = (const float*)d_in[14];
  const float* kr2 = (const float*)d_in[15];

  char* p = (char*)d_ws;
  auto alloc = [&](size_t bytes) {
    char* q = p;
    p += (bytes + 255) & ~(size_t)255;
    return q;
  };
  float* yf = (float*)alloc(8ull * 512 * 1024 * 4);      // 16 MB [B,C,N]
  u16* ynbf = (u16*)alloc(8192ull * 512 * 2);            // 8 MB  [B*N, C]
  u16* xsbf = (u16*)alloc(8192ull * 512 * 2);            // 8 MB  [B*N, C]
  u16* qwb = (u16*)alloc(512ull * 512 * 2);
  u16* kvwb = (u16*)alloc(1024ull * 512 * 2);
  u16* pwb = (u16*)alloc(512ull * 512 * 2);
  u16* qbf = (u16*)alloc(8192ull * 512 * 2);             // 8 MB
  u16* kvbf = (u16*)alloc(8192ull * 1024 * 2);           // 16 MB
  u16* vTb = (u16*)alloc(8ull * 8 * 64 * 1024 * 2);      // 8 MB [B,H,64,N]
  u16* aobf = (u16*)alloc(8192ull * 512 * 2);            // 8 MB
  float* projf = (float*)alloc(8192ull * 512 * 4);       // 16 MB

  cvt_bf<<<512, 256, 0, stream>>>(q_w, qwb, 512 * 512);
  cvt_bf<<<512, 256, 0, stream>>>(kv_w, kvwb, 1024 * 512);
  cvt_bf<<<512, 256, 0, stream>>>(proj_w, pwb, 512 * 512);
  conv_kernel<<<8 * 512, 256, 0, stream>>>(y, c1w, c1b, c2w, c2b, c3w, c3b, yf);
  ln_kernel<<<512, 256, 0, stream>>>(yf, ln_w, ln_b, ynbf);
  xpose_x<<<8 * 16 * 32, 256, 0, stream>>>(x, xsbf);
  gemm_nt<<<64 * 4, 256, 0, stream>>>(xsbf, qwb, qbf, 8192, 512, 512, 1);
  gemm_nt<<<64 * 8, 256, 0, stream>>>(ynbf, kvwb, kvbf, 8192, 1024, 512, 1);
  xpose_v<<<64 * 16, 256, 0, stream>>>(kvbf, vTb);
  attn_kernel<<<64 * 64, 256, 0, stream>>>(qbf, kvbf, vTb, aobf, kr1, kr2);
  gemm_nt<<<64 * 4, 256, 0, stream>>>(aobf, pwb, projf, 8192, 512, 512, 0);
  xpose_out<<<8 * 16 * 32, 256, 0, stream>>>(projf, x, proj_b, (float*)d_out);
}

// Round 2
// 418.020 us; speedup vs baseline: 1.3297x; 1.3297x over previous
//
#include <hip/hip_runtime.h>

typedef unsigned short u16;
typedef unsigned int u32;
typedef short v8s __attribute__((ext_vector_type(8)));
typedef float v4f __attribute__((ext_vector_type(4)));

#define MFMA16(a, b, c) __builtin_amdgcn_mfma_f32_16x16x32_bf16(a, b, c, 0, 0, 0)

__device__ __forceinline__ u16 f2bf(float f) {
  u32 u = __float_as_uint(f);
  u32 r = (u + 0x7fffu + ((u >> 16) & 1u)) >> 16;
  return (u16)r;
}
__device__ __forceinline__ float bf2f(u16 s) {
  return __uint_as_float(((u32)s) << 16);
}

// ---------------------------------------------------------------------------
// generic f32 -> bf16 convert
__global__ __launch_bounds__(256) void cvt_bf(const float* __restrict__ in,
                                              u16* __restrict__ out, int n) {
  for (int i = blockIdx.x * 256 + threadIdx.x; i < n; i += gridDim.x * 256)
    out[i] = f2bf(in[i]);
}

// ---------------------------------------------------------------------------
// fused depthwise conv 3x3 + 5x5 + 7x7 (stride 1, same padding), one WG per (b,c)
__global__ __launch_bounds__(256) void conv_kernel(
    const float* __restrict__ y, const float* __restrict__ w1, const float* __restrict__ b1,
    const float* __restrict__ w2, const float* __restrict__ b2,
    const float* __restrict__ w3, const float* __restrict__ b3, float* __restrict__ yf) {
  __shared__ float img[38 * 40];
  __shared__ float wl[84];
  int blk = blockIdx.x;           // b*512 + c
  int c = blk & 511;
  int t = threadIdx.x;
  const float* ybase = &y[(size_t)blk * 1024];
  for (int idx = t; idx < 38 * 40; idx += 256) {
    int row = idx / 40, col = idx - row * 40;
    float v = 0.f;
    int gh = row - 3, gw = col - 3;
    if (col < 38 && gh >= 0 && gh < 32 && gw >= 0 && gw < 32) v = ybase[gh * 32 + gw];
    if (col < 38) img[idx] = v;
  }
  if (t < 49) wl[t] = w3[c * 49 + t];
  else if (t < 74) wl[t] = w2[c * 25 + (t - 49)];
  else if (t < 83) wl[t] = w1[c * 9 + (t - 74)];
  float bias = b1[c] + b2[c] + b3[c];
  __syncthreads();
  for (int p = t; p < 1024; p += 256) {
    int hh = p >> 5, ww = p & 31;
    float acc = bias;
#pragma unroll
    for (int i = 0; i < 7; i++)
#pragma unroll
      for (int j = 0; j < 7; j++)
        acc += img[(hh + i) * 40 + ww + j] * wl[i * 7 + j];
#pragma unroll
    for (int i = 0; i < 5; i++)
#pragma unroll
      for (int j = 0; j < 5; j++)
        acc += img[(hh + 1 + i) * 40 + ww + 1 + j] * wl[49 + i * 5 + j];
#pragma unroll
    for (int i = 0; i < 3; i++)
#pragma unroll
      for (int j = 0; j < 3; j++)
        acc += img[(hh + 2 + i) * 40 + ww + 2 + j] * wl[74 + i * 3 + j];
    yf[(size_t)blk * 1024 + p] = acc;
  }
}

// ---------------------------------------------------------------------------
// LayerNorm over C=512 for 16 pixels per WG; yf [B,C,N] f32 -> yn [B*N, C] bf16
__global__ __launch_bounds__(256) void ln_kernel(const float* __restrict__ yf,
                                                 const float* __restrict__ lnw,
                                                 const float* __restrict__ lnb,
                                                 u16* __restrict__ ynbf) {
  __shared__ float T[512][17];
  __shared__ float ps1[16][16], ps2[16][16];
  __shared__ float mu_s[16], rs_s[16];
  int blk = blockIdx.x;  // b*64 + n-group
  int b = blk >> 6;
  int n0 = (blk & 63) << 4;
  int t = threadIdx.x;
  for (int idx = t; idx < 8192; idx += 256) {
    int c = idx >> 4, j = idx & 15;
    T[c][j] = yf[((size_t)(b * 512 + c)) * 1024 + n0 + j];
  }
  __syncthreads();
  {
    int j = t & 15, part = t >> 4;
    float s1 = 0.f, s2 = 0.f;
#pragma unroll 4
    for (int cc = 0; cc < 32; cc++) {
      float v = T[part * 32 + cc][j];
      s1 += v;
      s2 += v * v;
    }
    ps1[part][j] = s1;
    ps2[part][j] = s2;
  }
  __syncthreads();
  if (t < 16) {
    float a1 = 0.f, a2 = 0.f;
#pragma unroll
    for (int p = 0; p < 16; p++) { a1 += ps1[p][t]; a2 += ps2[p][t]; }
    float mu = a1 * (1.f / 512.f);
    float var = a2 * (1.f / 512.f) - mu * mu;
    mu_s[t] = mu;
    rs_s[t] = rsqrtf(var + 1e-5f);
  }
  __syncthreads();
  for (int idx = t; idx < 8192; idx += 256) {
    int c = idx & 511, jj = idx >> 9;
    float v = (T[c][jj] - mu_s[jj]) * rs_s[jj] * lnw[c] + lnb[c];
    ynbf[((size_t)(b * 1024 + n0 + jj)) * 512 + c] = f2bf(v);
  }
}

// ---------------------------------------------------------------------------
// x [B,C,N] f32 -> xs [B*N, C] bf16 (transpose + convert)
__global__ __launch_bounds__(256) void xpose_x(const float* __restrict__ x,
                                               u16* __restrict__ xsbf) {
  __shared__ float T[32][33];
  int blk = blockIdx.x;  // ((b*16 + cb)*32 + nb)
  int nb = blk & 31, cb = (blk >> 5) & 15, b = blk >> 9;
  int c0 = cb * 32, n0 = nb * 32;
  int t = threadIdx.x;
  for (int idx = t; idx < 1024; idx += 256) {
    int ci = idx >> 5, nj = idx & 31;
    T[ci][nj] = x[((size_t)(b * 512 + c0 + ci)) * 1024 + n0 + nj];
  }
  __syncthreads();
  for (int idx = t; idx < 1024; idx += 256) {
    int nj = idx >> 5, ci = idx & 31;
    xsbf[((size_t)(b * 1024 + n0 + nj)) * 512 + c0 + ci] = f2bf(T[ci][nj]);
  }
}

// ---------------------------------------------------------------------------
// v half of kv [B*N, 1024] bf16 -> vT [B,H,64,1024] bf16
__global__ __launch_bounds__(256) void xpose_v(const u16* __restrict__ kvbf,
                                               u16* __restrict__ vT) {
  __shared__ u16 T[64][72];
  int blk = blockIdx.x;  // (b*8+h)*16 + nt
  int nt = blk & 15, bh = blk >> 4;
  int b = bh >> 3, h = bh & 7;
  int n0 = nt * 64;
  int t = threadIdx.x;
  for (int idx = t; idx < 4096; idx += 256) {
    int ni = idx >> 6, dj = idx & 63;
    T[ni][dj] = kvbf[((size_t)(b * 1024 + n0 + ni)) * 1024 + 512 + h * 64 + dj];
  }
  __syncthreads();
  for (int idx = t; idx < 4096; idx += 256) {
    int dj = idx >> 6, ni = idx & 63;
    vT[((size_t)(bh * 64 + dj)) * 1024 + n0 + ni] = T[ni][dj];
  }
}

// ---------------------------------------------------------------------------
// bf16 NT GEMM: C[M,N] = A[M,K] * B[N,K]^T ; out f32 or bf16
__global__ __launch_bounds__(256) void gemm_nt(const u16* __restrict__ A,
                                               const u16* __restrict__ B, void* __restrict__ Cout,
                                               int M, int N, int K, int outBF) {
  __shared__ u16 As[128 * 40];
  __shared__ u16 Bs[128 * 40];
  int blk = blockIdx.x;
  int nblk = N >> 7;
  int m0 = (blk / nblk) << 7, n0 = (blk % nblk) << 7;
  int t = threadIdx.x;
  int lane = t & 63, w = t >> 6;
  int wr = w >> 1, wc = w & 1;
  int lr = lane & 15, kr = lane >> 4;

  v4f acc[4][4];
#pragma unroll
  for (int i = 0; i < 4; i++)
#pragma unroll
    for (int j = 0; j < 4; j++) acc[i][j] = (v4f){0.f, 0.f, 0.f, 0.f};

  const int r0 = t >> 2, s0 = (t & 3) * 8;
  const int r1 = r0 + 64;

  for (int k0 = 0; k0 < K; k0 += 32) {
    int4 a0 = *(const int4*)&A[(size_t)(m0 + r0) * K + k0 + s0];
    int4 a1 = *(const int4*)&A[(size_t)(m0 + r1) * K + k0 + s0];
    int4 b0 = *(const int4*)&B[(size_t)(n0 + r0) * K + k0 + s0];
    int4 b1 = *(const int4*)&B[(size_t)(n0 + r1) * K + k0 + s0];
    __syncthreads();
    *(int4*)&As[r0 * 40 + s0] = a0;
    *(int4*)&As[r1 * 40 + s0] = a1;
    *(int4*)&Bs[r0 * 40 + s0] = b0;
    *(int4*)&Bs[r1 * 40 + s0] = b1;
    __syncthreads();
    v8s af[4], bfr[4];
#pragma unroll
    for (int i = 0; i < 4; i++) af[i] = *(const v8s*)&As[(wr * 64 + i * 16 + lr) * 40 + kr * 8];
#pragma unroll
    for (int i = 0; i < 4; i++) bfr[i] = *(const v8s*)&Bs[(wc * 64 + i * 16 + lr) * 40 + kr * 8];
#pragma unroll
    for (int i = 0; i < 4; i++)
#pragma unroll
      for (int j = 0; j < 4; j++) acc[i][j] = MFMA16(af[i], bfr[j], acc[i][j]);
  }
#pragma unroll
  for (int i = 0; i < 4; i++)
#pragma unroll
    for (int j = 0; j < 4; j++) {
      int row = m0 + wr * 64 + i * 16 + kr * 4;
      int col = n0 + wc * 64 + j * 16 + lr;
#pragma unroll
      for (int q = 0; q < 4; q++) {
        float v = acc[i][j][q];
        if (outBF) ((u16*)Cout)[(size_t)(row + q) * N + col] = f2bf(v);
        else ((float*)Cout)[(size_t)(row + q) * N + col] = v;
      }
    }
}

// ---------------------------------------------------------------------------
// fused attention: per WG = (b, h, 16 q-rows). S=qK^T/8 (bf16 LDS), exact
// radix-select top-k thresholds (k1,k2) with wave-wide register-resident
// selection, combined masked softmax weights, PV via MFMA, bf16 out [B*N, C].
__global__ __launch_bounds__(256) void attn_kernel(
    const u16* __restrict__ qbf, const u16* __restrict__ kvbf, const u16* __restrict__ vT,
    u16* __restrict__ aobf, const float* __restrict__ kr1p, const float* __restrict__ kr2p) {
  __shared__ u16 Sb[16][1032];
  __shared__ __align__(16) char pool[16384];  // union: qtile / per-wave hists / opart

  int blk = blockIdx.x;
  // bijective XCD swizzle: each XCD gets a contiguous bh range so the 64 WGs
  // sharing one (b,h) K/V slice (256KB) hit the same L2.
  int xq = blk & 7, jq = blk >> 3;
  int bh = xq * 8 + (jq & 7);
  int rb = jq >> 3;
  int b = bh >> 3, h = bh & 7;
  int n0 = rb * 16;
  int t = threadIdx.x, lane = t & 63, w = t >> 6;
  int lr = lane & 15, kr = lane >> 4;

  u16 (*qtile)[64] = (u16(*)[64])pool;
  u32* ha = (u32*)pool + (size_t)w * 780;
  u32* hb1 = ha + 260;
  u32* hb2 = ha + 520;
  float (*opart)[16][64] = (float(*)[16][64])pool;

  float sg1 = 1.f / (1.f + __expf(-kr1p[0]));
  int k1 = min(max((int)(1024.f * sg1), 1), 1024);
  float sg2 = 1.f / (1.f + __expf(-kr2p[0]));
  int k2 = min(max((int)(1024.f * sg2), 1), 1024);

  {  // load q tile [16][64]
    int r = t >> 4, seg = t & 15;
    *(uint2*)&qtile[r][seg * 4] =
        *(const uint2*)&qbf[(size_t)(b * 1024 + n0 + r) * 512 + h * 64 + seg * 4];
  }
  __syncthreads();

  {  // Phase 1: S = q K^T * 0.125 -> bf16 LDS
    v8s a0 = *(const v8s*)&qtile[lr][kr * 8];
    v8s a1 = *(const v8s*)&qtile[lr][32 + kr * 8];
    int cbase = w * 256;
#pragma unroll
    for (int cf = 0; cf < 16; cf++) {
      int c0 = cbase + cf * 16;
      const u16* kp = &kvbf[(size_t)(b * 1024 + c0 + lr) * 1024 + h * 64];
      v8s b0 = *(const v8s*)&kp[kr * 8];
      v8s b1 = *(const v8s*)&kp[32 + kr * 8];
      v4f acc = (v4f){0.f, 0.f, 0.f, 0.f};
      acc = MFMA16(a0, b0, acc);
      acc = MFMA16(a1, b1, acc);
#pragma unroll
      for (int j = 0; j < 4; j++) Sb[kr * 4 + j][c0 + lr] = f2bf(acc[j] * 0.125f);
    }
  }
  __syncthreads();

  {  // Phase 2: wave w handles rows 4w..4w+3 sequentially, register-resident
    int l = lane;
#pragma unroll 1
    for (int i = 0; i < 4; i++) {
      int rr = w * 4 + i;
      const u16* rowp = &Sb[rr][l * 16];
      uint4 r0 = *(const uint4*)rowp;
      uint4 r1 = *(const uint4*)(rowp + 8);
      u32 wd[8] = {r0.x, r0.y, r0.z, r0.w, r1.x, r1.y, r1.z, r1.w};
      u32 key[16];
      float v[16];
#pragma unroll
      for (int jj = 0; jj < 16; jj++) {
        u16 s = (u16)(wd[jj >> 1] >> ((jj & 1) * 16));
        key[jj] = (s & 0x8000u) ? (u32)(u16)(~s) : (u32)(s | 0x8000u);
        v[jj] = bf2f(s);
      }
      float mf = v[0];
#pragma unroll
      for (int jj = 1; jj < 16; jj++) mf = fmaxf(mf, v[jj]);
#pragma unroll
      for (int d = 1; d < 64; d <<= 1) mf = fmaxf(mf, __shfl_xor(mf, d));

      // pass-1 histogram over key high byte
      *(uint4*)&ha[4 * l] = make_uint4(0u, 0u, 0u, 0u);
      asm volatile("s_waitcnt lgkmcnt(0)" ::: "memory");
#pragma unroll
      for (int jj = 0; jj < 16; jj++) atomicAdd(&ha[key[jj] >> 8], 1u);
      asm volatile("s_waitcnt lgkmcnt(0)" ::: "memory");

      uint4 hh;
      u32 suf = 0, sufn = 0;
      auto do_scan = [&](const u32* hp) {
        hh = *(const uint4*)&hp[4 * l];
        u32 s = hh.x + hh.y + hh.z + hh.w;
        suf = s;
#pragma unroll
        for (int d = 1; d < 64; d <<= 1) {
          u32 o = __shfl_down(suf, d);
          if (l + d < 64) suf += o;
        }
        u32 tmp = __shfl_down(suf, 1);
        sufn = (l == 63) ? 0u : tmp;
      };
      auto cross = [&](u32 kk) -> uint2 {
        u32 c3 = sufn + hh.w;
        u32 c2 = c3 + hh.z;
        u32 c1 = c2 + hh.y;
        u32 c0 = c1 + hh.x;
        u32 pk = 0;
        bool f = false;
        if (c0 >= kk && c1 < kk) { f = true; pk = ((u32)(4 * l + 0) << 16) | (kk - c1); }
        else if (c1 >= kk && c2 < kk) { f = true; pk = ((u32)(4 * l + 1) << 16) | (kk - c2); }
        else if (c2 >= kk && c3 < kk) { f = true; pk = ((u32)(4 * l + 2) << 16) | (kk - c3); }
        else if (c3 >= kk && sufn < kk) { f = true; pk = ((u32)(4 * l + 3) << 16) | (kk - sufn); }
        unsigned long long bal = __ballot(f);
        int src = (int)__ffsll((unsigned long long)bal) - 1;
        pk = __shfl(pk, src);
        return make_uint2(pk >> 16, pk & 0xffffu);
      };

      do_scan(ha);
      uint2 p1 = cross((u32)k1);
      uint2 p2 = cross((u32)k2);

      // pass-2 histograms over low byte, restricted to the crossing prefix
      *(uint4*)&hb1[4 * l] = make_uint4(0u, 0u, 0u, 0u);
      *(uint4*)&hb2[4 * l] = make_uint4(0u, 0u, 0u, 0u);
      asm volatile("s_waitcnt lgkmcnt(0)" ::: "memory");
      bool two = (p2.x != p1.x);
#pragma unroll
      for (int jj = 0; jj < 16; jj++) {
        u32 hi = key[jj] >> 8;
        if (hi == p1.x) atomicAdd(&hb1[key[jj] & 255u], 1u);
        if (two && hi == p2.x) atomicAdd(&hb2[key[jj] & 255u], 1u);
      }
      asm volatile("s_waitcnt lgkmcnt(0)" ::: "memory");

      do_scan(hb1);
      uint2 q1 = cross(p1.y);
      u32 t1u = (p1.x << 8) | q1.x;
      u32 t2u;
      if (!two) {
        uint2 q2 = cross(p2.y);
        t2u = (p1.x << 8) | q2.x;
      } else {
        do_scan(hb2);
        uint2 q2 = cross(p2.y);
        t2u = (p2.x << 8) | q2.x;
      }

      // masked softmax weights (exp computed once, reused)
      float ev[16];
      float z1 = 0.f, z2 = 0.f;
#pragma unroll
      for (int jj = 0; jj < 16; jj++) {
        ev[jj] = __expf(v[jj] - mf);
        if (key[jj] >= t1u) z1 += ev[jj];
        if (key[jj] >= t2u) z2 += ev[jj];
      }
#pragma unroll
      for (int d = 1; d < 64; d <<= 1) {
        z1 += __shfl_xor(z1, d);
        z2 += __shfl_xor(z2, d);
      }
      float w1 = 0.6f / z1, w2 = 0.4f / z2;
      u32 ow[8];
#pragma unroll
      for (int jj = 0; jj < 16; jj++) {
        float wv = 0.f;
        if (key[jj] >= t1u) wv = ev[jj] * w1;
        if (key[jj] >= t2u) wv += ev[jj] * w2;
        u32 bb = (u32)f2bf(wv);
        if (jj & 1) ow[jj >> 1] |= bb << 16;
        else ow[jj >> 1] = bb;
      }
      *(uint4*)&Sb[rr][l * 16] = make_uint4(ow[0], ow[1], ow[2], ow[3]);
      *(uint4*)&Sb[rr][l * 16 + 8] = make_uint4(ow[4], ow[5], ow[6], ow[7]);
    }
  }
  __syncthreads();

  {  // Phase 3: PV, wave w covers context slice [w*256, w*256+256)
    v4f acc[4];
#pragma unroll
    for (int nf = 0; nf < 4; nf++) acc[nf] = (v4f){0.f, 0.f, 0.f, 0.f};
    int cw = w * 256;
    const u16* vbase = &vT[(size_t)(bh * 64) * 1024];
#pragma unroll
    for (int ks = 0; ks < 8; ks++) {
      int c0 = cw + ks * 32;
      v8s a = *(const v8s*)&Sb[lr][c0 + kr * 8];
#pragma unroll
      for (int nf = 0; nf < 4; nf++) {
        v8s bb = *(const v8s*)&vbase[(size_t)(nf * 16 + lr) * 1024 + c0 + kr * 8];
        acc[nf] = MFMA16(a, bb, acc[nf]);
      }
    }
#pragma unroll
    for (int nf = 0; nf < 4; nf++)
#pragma unroll
      for (int j = 0; j < 4; j++) opart[w][kr * 4 + j][nf * 16 + lr] = acc[nf][j];
  }
  __syncthreads();
  {
    int rr = t >> 4, d0 = (t & 15) * 4;
#pragma unroll
    for (int q = 0; q < 4; q++) {
      float v = opart[0][rr][d0 + q] + opart[1][rr][d0 + q] + opart[2][rr][d0 + q] +
                opart[3][rr][d0 + q];
      aobf[(size_t)(b * 1024 + n0 + rr) * 512 + h * 64 + d0 + q] = f2bf(v);
    }
  }
}

// ---------------------------------------------------------------------------
// final: out[b,c,n] = proj_gemm[(b,n),c] + proj_b[c] + x[b,c,n]
__global__ __launch_bounds__(256) void xpose_out(const float* __restrict__ G,
                                                 const float* __restrict__ x,
                                                 const float* __restrict__ pb,
                                                 float* __restrict__ out) {
  __shared__ float T[32][33];
  int blk = blockIdx.x;  // ((b*16 + cb)*32 + nb)
  int nb = blk & 31, cb = (blk >> 5) & 15, b = blk >> 9;
  int c0 = cb * 32, n0 = nb * 32;
  int t = threadIdx.x;
  for (int idx = t; idx < 1024; idx += 256) {
    int nj = idx >> 5, ci = idx & 31;
    T[ci][nj] = G[((size_t)(b * 1024 + n0 + nj)) * 512 + c0 + ci];
  }
  __syncthreads();
  for (int idx = t; idx < 1024; idx += 256) {
    int ci = idx >> 5, nj = idx & 31;
    size_t o = ((size_t)(b * 512 + c0 + ci)) * 1024 + n0 + nj;
    out[o] = T[ci][nj] + pb[c0 + ci] + x[o];
  }
}

// ---------------------------------------------------------------------------
extern "C" void kernel_launch(void* const* d_in, const int* in_sizes, int n_in,
                              void* d_out, int out_size, void* d_ws, size_t ws_size,
                              hipStream_t stream) {
  (void)in_sizes; (void)n_in; (void)out_size; (void)ws_size;
  const float* x = (const float*)d_in[0];
  const float* y = (const float*)d_in[1];
  const float* q_w = (const float*)d_in[2];
  const float* kv_w = (const float*)d_in[3];
  const float* proj_w = (const float*)d_in[4];
  const float* proj_b = (const float*)d_in[5];
  const float* c1w = (const float*)d_in[6];
  const float* c1b = (const float*)d_in[7];
  const float* c2w = (const float*)d_in[8];
  const float* c2b = (const float*)d_in[9];
  const float* c3w = (const float*)d_in[10];
  const float* c3b = (const float*)d_in[11];
  const float* ln_w = (const float*)d_in[12];
  const float* ln_b = (const float*)d_in[13];
  const float* kr1 = (const float*)d_in[14];
  const float* kr2 = (const float*)d_in[15];

  char* p = (char*)d_ws;
  auto alloc = [&](size_t bytes) {
    char* q = p;
    p += (bytes + 255) & ~(size_t)255;
    return q;
  };
  float* yf = (float*)alloc(8ull * 512 * 1024 * 4);      // 16 MB [B,C,N]
  u16* ynbf = (u16*)alloc(8192ull * 512 * 2);            // 8 MB  [B*N, C]
  u16* xsbf = (u16*)alloc(8192ull * 512 * 2);            // 8 MB  [B*N, C]
  u16* qwb = (u16*)alloc(512ull * 512 * 2);
  u16* kvwb = (u16*)alloc(1024ull * 512 * 2);
  u16* pwb = (u16*)alloc(512ull * 512 * 2);
  u16* qbf = (u16*)alloc(8192ull * 512 * 2);             // 8 MB
  u16* kvbf = (u16*)alloc(8192ull * 1024 * 2);           // 16 MB
  u16* vTb = (u16*)alloc(8ull * 8 * 64 * 1024 * 2);      // 8 MB [B,H,64,N]
  u16* aobf = (u16*)alloc(8192ull * 512 * 2);            // 8 MB
  float* projf = (float*)alloc(8192ull * 512 * 4);       // 16 MB

  cvt_bf<<<512, 256, 0, stream>>>(q_w, qwb, 512 * 512);
  cvt_bf<<<512, 256, 0, stream>>>(kv_w, kvwb, 1024 * 512);
  cvt_bf<<<512, 256, 0, stream>>>(proj_w, pwb, 512 * 512);
  conv_kernel<<<8 * 512, 256, 0, stream>>>(y, c1w, c1b, c2w, c2b, c3w, c3b, yf);
  ln_kernel<<<512, 256, 0, stream>>>(yf, ln_w, ln_b, ynbf);
  xpose_x<<<8 * 16 * 32, 256, 0, stream>>>(x, xsbf);
  gemm_nt<<<64 * 4, 256, 0, stream>>>(xsbf, qwb, qbf, 8192, 512, 512, 1);
  gemm_nt<<<64 * 8, 256, 0, stream>>>(ynbf, kvwb, kvbf, 8192, 1024, 512, 1);
  xpose_v<<<64 * 16, 256, 0, stream>>>(kvbf, vTb);
  attn_kernel<<<64 * 64, 256, 0, stream>>>(qbf, kvbf, vTb, aobf, kr1, kr2);
  gemm_nt<<<64 * 4, 256, 0, stream>>>(aobf, pwb, projf, 8192, 512, 512, 0);
  xpose_out<<<8 * 16 * 32, 256, 0, stream>>>(projf, x, proj_b, (float*)d_out);
}

// Round 4
// 411.946 us; speedup vs baseline: 1.3493x; 1.0147x over previous
//
#include <hip/hip_runtime.h>

typedef unsigned short u16;
typedef unsigned int u32;
typedef short v8s __attribute__((ext_vector_type(8)));
typedef float v4f __attribute__((ext_vector_type(4)));

#define MFMA16(a, b, c) __builtin_amdgcn_mfma_f32_16x16x32_bf16(a, b, c, 0, 0, 0)

__device__ __forceinline__ u16 f2bf(float f) {
  u32 u = __float_as_uint(f);
  u32 r = (u + 0x7fffu + ((u >> 16) & 1u)) >> 16;
  return (u16)r;
}
__device__ __forceinline__ float bf2f(u16 s) {
  return __uint_as_float(((u32)s) << 16);
}

// ---------------------------------------------------------------------------
// fused f32 -> bf16 convert of the three weight matrices
__global__ __launch_bounds__(256) void cvt3(const float* __restrict__ a, u16* __restrict__ oa,
                                            int na, const float* __restrict__ b,
                                            u16* __restrict__ ob, int nb,
                                            const float* __restrict__ c, u16* __restrict__ oc,
                                            int nc) {
  int total = na + nb + nc;
  for (int i = blockIdx.x * 256 + threadIdx.x; i < total; i += gridDim.x * 256) {
    if (i < na) oa[i] = f2bf(a[i]);
    else if (i < na + nb) ob[i - na] = f2bf(b[i - na]);
    else oc[i - na - nb] = f2bf(c[i - na - nb]);
  }
}

// ---------------------------------------------------------------------------
// fused depthwise conv 3x3 + 5x5 + 7x7 (stride 1, same padding), one WG per (b,c)
__global__ __launch_bounds__(256) void conv_kernel(
    const float* __restrict__ y, const float* __restrict__ w1, const float* __restrict__ b1,
    const float* __restrict__ w2, const float* __restrict__ b2,
    const float* __restrict__ w3, const float* __restrict__ b3, float* __restrict__ yf) {
  __shared__ float img[38 * 40];
  __shared__ float wl[84];
  int blk = blockIdx.x;           // b*512 + c
  int c = blk & 511;
  int t = threadIdx.x;
  const float* ybase = &y[(size_t)blk * 1024];
  for (int idx = t; idx < 38 * 40; idx += 256) {
    int row = idx / 40, col = idx - row * 40;
    float v = 0.f;
    int gh = row - 3, gw = col - 3;
    if (col < 38 && gh >= 0 && gh < 32 && gw >= 0 && gw < 32) v = ybase[gh * 32 + gw];
    if (col < 38) img[idx] = v;
  }
  if (t < 49) wl[t] = w3[c * 49 + t];
  else if (t < 74) wl[t] = w2[c * 25 + (t - 49)];
  else if (t < 83) wl[t] = w1[c * 9 + (t - 74)];
  float bias = b1[c] + b2[c] + b3[c];
  __syncthreads();
  for (int p = t; p < 1024; p += 256) {
    int hh = p >> 5, ww = p & 31;
    float acc = bias;
#pragma unroll
    for (int i = 0; i < 7; i++)
#pragma unroll
      for (int j = 0; j < 7; j++)
        acc += img[(hh + i) * 40 + ww + j] * wl[i * 7 + j];
#pragma unroll
    for (int i = 0; i < 5; i++)
#pragma unroll
      for (int j = 0; j < 5; j++)
        acc += img[(hh + 1 + i) * 40 + ww + 1 + j] * wl[49 + i * 5 + j];
#pragma unroll
    for (int i = 0; i < 3; i++)
#pragma unroll
      for (int j = 0; j < 3; j++)
        acc += img[(hh + 2 + i) * 40 + ww + 2 + j] * wl[74 + i * 3 + j];
    yf[(size_t)blk * 1024 + p] = acc;
  }
}

// ---------------------------------------------------------------------------
// LayerNorm over C=512 for 16 pixels per WG; yf [B,C,N] f32 -> yn [B*N, C] bf16
__global__ __launch_bounds__(256) void ln_kernel(const float* __restrict__ yf,
                                                 const float* __restrict__ lnw,
                                                 const float* __restrict__ lnb,
                                                 u16* __restrict__ ynbf) {
  __shared__ float T[512][17];
  __shared__ float ps1[16][16], ps2[16][16];
  __shared__ float mu_s[16], rs_s[16];
  int blk = blockIdx.x;  // b*64 + n-group
  int b = blk >> 6;
  int n0 = (blk & 63) << 4;
  int t = threadIdx.x;
  for (int idx = t; idx < 8192; idx += 256) {
    int c = idx >> 4, j = idx & 15;
    T[c][j] = yf[((size_t)(b * 512 + c)) * 1024 + n0 + j];
  }
  __syncthreads();
  {
    int j = t & 15, part = t >> 4;
    float s1 = 0.f, s2 = 0.f;
#pragma unroll 4
    for (int cc = 0; cc < 32; cc++) {
      float v = T[part * 32 + cc][j];
      s1 += v;
      s2 += v * v;
    }
    ps1[part][j] = s1;
    ps2[part][j] = s2;
  }
  __syncthreads();
  if (t < 16) {
    float a1 = 0.f, a2 = 0.f;
#pragma unroll
    for (int p = 0; p < 16; p++) { a1 += ps1[p][t]; a2 += ps2[p][t]; }
    float mu = a1 * (1.f / 512.f);
    float var = a2 * (1.f / 512.f) - mu * mu;
    mu_s[t] = mu;
    rs_s[t] = rsqrtf(var + 1e-5f);
  }
  __syncthreads();
  for (int idx = t; idx < 8192; idx += 256) {
    int c = idx & 511, jj = idx >> 9;
    float v = (T[c][jj] - mu_s[jj]) * rs_s[jj] * lnw[c] + lnb[c];
    ynbf[((size_t)(b * 1024 + n0 + jj)) * 512 + c] = f2bf(v);
  }
}

// ---------------------------------------------------------------------------
// x [B,C,N] f32 -> xs [B*N, C] bf16 (transpose + convert)
__global__ __launch_bounds__(256) void xpose_x(const float* __restrict__ x,
                                               u16* __restrict__ xsbf) {
  __shared__ float T[32][33];
  int blk = blockIdx.x;  // ((b*16 + cb)*32 + nb)
  int nb = blk & 31, cb = (blk >> 5) & 15, b = blk >> 9;
  int c0 = cb * 32, n0 = nb * 32;
  int t = threadIdx.x;
  for (int idx = t; idx < 1024; idx += 256) {
    int ci = idx >> 5, nj = idx & 31;
    T[ci][nj] = x[((size_t)(b * 512 + c0 + ci)) * 1024 + n0 + nj];
  }
  __syncthreads();
  for (int idx = t; idx < 1024; idx += 256) {
    int nj = idx >> 5, ci = idx & 31;
    xsbf[((size_t)(b * 1024 + n0 + nj)) * 512 + c0 + ci] = f2bf(T[ci][nj]);
  }
}

// ---------------------------------------------------------------------------
// v half of kv [B*N, 1024] bf16 -> vT [B,H,64,1024] bf16
__global__ __launch_bounds__(256) void xpose_v(const u16* __restrict__ kvbf,
                                               u16* __restrict__ vT) {
  __shared__ u16 T[64][72];
  int blk = blockIdx.x;  // (b*8+h)*16 + nt
  int nt = blk & 15, bh = blk >> 4;
  int b = bh >> 3, h = bh & 7;
  int n0 = nt * 64;
  int t = threadIdx.x;
  for (int idx = t; idx < 4096; idx += 256) {
    int ni = idx >> 6, dj = idx & 63;
    T[ni][dj] = kvbf[((size_t)(b * 1024 + n0 + ni)) * 1024 + 512 + h * 64 + dj];
  }
  __syncthreads();
  for (int idx = t; idx < 4096; idx += 256) {
    int dj = idx >> 6, ni = idx & 63;
    vT[((size_t)(bh * 64 + dj)) * 1024 + n0 + ni] = T[ni][dj];
  }
}

// ---------------------------------------------------------------------------
// bf16 NT GEMM, BM=128 BN=64 BK=32: C[M,N] = A[M,K] * B[N,K]^T ; out f32 or bf16
__global__ __launch_bounds__(256) void gemm_nt64(const u16* __restrict__ A,
                                                 const u16* __restrict__ B,
                                                 void* __restrict__ Cout, int M, int N, int K,
                                                 int outBF) {
  __shared__ u16 As[128 * 40];
  __shared__ u16 Bs[64 * 40];
  int blk = blockIdx.x;
  int nblk = N >> 6;
  int m0 = (blk / nblk) << 7, n0 = (blk % nblk) << 6;
  int t = threadIdx.x;
  int lane = t & 63, w = t >> 6;
  int wr = w >> 1, wc = w & 1;
  int lr = lane & 15, kr = lane >> 4;

  v4f acc[4][2];
#pragma unroll
  for (int i = 0; i < 4; i++)
#pragma unroll
    for (int j = 0; j < 2; j++) acc[i][j] = (v4f){0.f, 0.f, 0.f, 0.f};

  const int r0 = t >> 2, s0 = (t & 3) * 8;

  for (int k0 = 0; k0 < K; k0 += 32) {
    int4 a0 = *(const int4*)&A[(size_t)(m0 + r0) * K + k0 + s0];
    int4 a1 = *(const int4*)&A[(size_t)(m0 + r0 + 64) * K + k0 + s0];
    int4 b0 = *(const int4*)&B[(size_t)(n0 + r0) * K + k0 + s0];
    __syncthreads();
    *(int4*)&As[r0 * 40 + s0] = a0;
    *(int4*)&As[(r0 + 64) * 40 + s0] = a1;
    *(int4*)&Bs[r0 * 40 + s0] = b0;
    __syncthreads();
    v8s af[4], bfr[2];
#pragma unroll
    for (int i = 0; i < 4; i++) af[i] = *(const v8s*)&As[(wr * 64 + i * 16 + lr) * 40 + kr * 8];
#pragma unroll
    for (int j = 0; j < 2; j++) bfr[j] = *(const v8s*)&Bs[(wc * 32 + j * 16 + lr) * 40 + kr * 8];
#pragma unroll
    for (int i = 0; i < 4; i++)
#pragma unroll
      for (int j = 0; j < 2; j++) acc[i][j] = MFMA16(af[i], bfr[j], acc[i][j]);
  }
#pragma unroll
  for (int i = 0; i < 4; i++)
#pragma unroll
    for (int j = 0; j < 2; j++) {
      int row = m0 + wr * 64 + i * 16 + kr * 4;
      int col = n0 + wc * 32 + j * 16 + lr;
#pragma unroll
      for (int q = 0; q < 4; q++) {
        float v = acc[i][j][q];
        if (outBF) ((u16*)Cout)[(size_t)(row + q) * N + col] = f2bf(v);
        else ((float*)Cout)[(size_t)(row + q) * N + col] = v;
      }
    }
}

// ---------------------------------------------------------------------------
// fused attention: per WG = (b, h, 16 q-rows). S = (K q^T)/8 swapped-MFMA ->
// packed bf16 LDS; register-resident dual radix-select (replicated wave-
// private histograms, packed dual pass-2), masked softmax weights in-place,
// PV via MFMA, bf16 out [B*N, C].
__global__ __launch_bounds__(256) void attn_kernel(
    const u16* __restrict__ qbf, const u16* __restrict__ kvbf, const u16* __restrict__ vT,
    u16* __restrict__ aobf, const float* __restrict__ kr1p, const float* __restrict__ kr2p) {
  __shared__ u16 Sb[16][1032];
  __shared__ __align__(16) char pool[16384];  // union: qtile / per-wave hists / opart

  int blk = blockIdx.x;
  int xq = blk & 7, jq = blk >> 3;
  int bh = xq * 8 + (jq & 7);
  int rb = jq >> 3;
  int b = bh >> 3, h = bh & 7;
  int n0 = rb * 16;
  int t = threadIdx.x, lane = t & 63, w = t >> 6;
  int lr = lane & 15, kr = lane >> 4;

  u16 (*qtile)[64] = (u16(*)[64])pool;
  u32* hw = (u32*)pool + (size_t)w * 1024;       // per-wave: 4 copies x 256 bins
  u32* hcopy = hw + (lane >> 4) * 256;           // this lane's private copy
  float (*opart)[16][64] = (float(*)[16][64])pool;

  float sg1 = 1.f / (1.f + __expf(-kr1p[0]));
  int k1 = min(max((int)(1024.f * sg1), 1), 1024);
  float sg2 = 1.f / (1.f + __expf(-kr2p[0]));
  int k2 = min(max((int)(1024.f * sg2), 1), 1024);

  {  // load q tile [16][64]
    int r = t >> 4, seg = t & 15;
    *(uint2*)&qtile[r][seg * 4] =
        *(const uint2*)&qbf[(size_t)(b * 1024 + n0 + r) * 512 + h * 64 + seg * 4];
  }
  __syncthreads();

  {  // Phase 1: S^T tiles via mfma(K, Q); lane holds 4 consecutive ctx cols of
     // one q-row -> packed b64 stores.
    v8s qf0 = *(const v8s*)&qtile[lr][kr * 8];
    v8s qf1 = *(const v8s*)&qtile[lr][32 + kr * 8];
    int cbase = w * 256;
#pragma unroll
    for (int cf = 0; cf < 16; cf++) {
      int c0 = cbase + cf * 16;
      const u16* kp = &kvbf[(size_t)(b * 1024 + c0 + lr) * 1024 + h * 64];
      v8s kf0 = *(const v8s*)&kp[kr * 8];
      v8s kf1 = *(const v8s*)&kp[32 + kr * 8];
      v4f acc = (v4f){0.f, 0.f, 0.f, 0.f};
      acc = MFMA16(kf0, qf0, acc);
      acc = MFMA16(kf1, qf1, acc);
      u32 p0 = (__float_as_uint(acc[0] * 0.125f) >> 16) |
               (__float_as_uint(acc[1] * 0.125f) & 0xffff0000u);
      u32 p1 = (__float_as_uint(acc[2] * 0.125f) >> 16) |
               (__float_as_uint(acc[3] * 0.125f) & 0xffff0000u);
      *(uint2*)&Sb[lr][c0 + kr * 4] = make_uint2(p0, p1);
    }
  }
  __syncthreads();

  {  // Phase 2: wave w handles rows 4w..4w+3 sequentially, register-resident
    int l = lane;
#pragma unroll 1
    for (int i = 0; i < 4; i++) {
      int rr = w * 4 + i;
      const u16* rowp = &Sb[rr][l * 16];
      uint4 r0 = *(const uint4*)rowp;
      uint4 r1 = *(const uint4*)(rowp + 8);
      u32 wd[8] = {r0.x, r0.y, r0.z, r0.w, r1.x, r1.y, r1.z, r1.w};
      u32 key[16];
#pragma unroll
      for (int p = 0; p < 8; p++) {
        u32 m = (wd[p] >> 15) & 0x10001u;
        u32 kp = wd[p] ^ (0x80008000u ^ (m * 0x7fffu));
        key[2 * p] = kp & 0xffffu;
        key[2 * p + 1] = kp >> 16;
      }
      u32 mx = key[0];
#pragma unroll
      for (int jj = 1; jj < 16; jj++) mx = max(mx, key[jj]);
#pragma unroll
      for (int d = 1; d < 64; d <<= 1) mx = max(mx, (u32)__shfl_xor((int)mx, d));
      u16 ms = (mx & 0x8000u) ? (u16)(mx & 0x7fffu) : (u16)(~mx);
      float mf = bf2f(ms);

      // pass-1 histogram over key high byte (4 replicated copies)
      {
        int cb = l * 16;
        uint4 z4 = make_uint4(0u, 0u, 0u, 0u);
        *(uint4*)&hw[cb] = z4;
        *(uint4*)&hw[cb + 4] = z4;
        *(uint4*)&hw[cb + 8] = z4;
        *(uint4*)&hw[cb + 12] = z4;
      }
      asm volatile("s_waitcnt lgkmcnt(0)" ::: "memory");
#pragma unroll
      for (int jj = 0; jj < 16; jj++) atomicAdd(&hcopy[key[jj] >> 8], 1u);
      asm volatile("s_waitcnt lgkmcnt(0)" ::: "memory");

      uint4 hh;
      u32 suf = 0, sufn = 0;
      auto do_scan = [&]() {
        uint4 h0 = *(const uint4*)&hw[4 * l];
        uint4 h1 = *(const uint4*)&hw[256 + 4 * l];
        uint4 h2 = *(const uint4*)&hw[512 + 4 * l];
        uint4 h3 = *(const uint4*)&hw[768 + 4 * l];
        hh.x = h0.x + h1.x + h2.x + h3.x;
        hh.y = h0.y + h1.y + h2.y + h3.y;
        hh.z = h0.z + h1.z + h2.z + h3.z;
        hh.w = h0.w + h1.w + h2.w + h3.w;
        suf = hh.x + hh.y + hh.z + hh.w;
#pragma unroll
        for (int d = 1; d < 64; d <<= 1) {
          u32 o = (u32)__shfl_down((int)suf, d);
          if (l + d < 64) suf += o;
        }
        u32 tmp = (u32)__shfl_down((int)suf, 1);
        sufn = (l == 63) ? 0u : tmp;
      };
      auto crossx = [&](u32 kk, int sh) -> uint2 {
        u32 hx = (hh.x >> sh) & 0xffffu, hy = (hh.y >> sh) & 0xffffu;
        u32 hz = (hh.z >> sh) & 0xffffu, hw4 = (hh.w >> sh) & 0xffffu;
        u32 sn = (sufn >> sh) & 0xffffu;
        u32 c3 = sn + hw4;
        u32 c2 = c3 + hz;
        u32 c1 = c2 + hy;
        u32 c0 = c1 + hx;
        u32 pk = 0;
        bool f = false;
        if (c0 >= kk && c1 < kk) { f = true; pk = ((u32)(4 * l + 0) << 16) | (kk - c1); }
        else if (c1 >= kk && c2 < kk) { f = true; pk = ((u32)(4 * l + 1) << 16) | (kk - c2); }
        else if (c2 >= kk && c3 < kk) { f = true; pk = ((u32)(4 * l + 2) << 16) | (kk - c3); }
        else if (c3 >= kk && sn < kk) { f = true; pk = ((u32)(4 * l + 3) << 16) | (kk - sn); }
        unsigned long long bal = __ballot(f);
        int src = (int)__ffsll(bal) - 1;
        pk = (u32)__shfl((int)pk, src);
        return make_uint2(pk >> 16, pk & 0xffffu);
      };

      do_scan();
      uint2 p1 = crossx((u32)k1, 0);
      uint2 p2 = crossx((u32)k2, 0);

      // pass-2: dual-k packed histogram over low byte within crossing bins
      {
        int cb = l * 16;
        uint4 z4 = make_uint4(0u, 0u, 0u, 0u);
        *(uint4*)&hw[cb] = z4;
        *(uint4*)&hw[cb + 4] = z4;
        *(uint4*)&hw[cb + 8] = z4;
        *(uint4*)&hw[cb + 12] = z4;
      }
      asm volatile("s_waitcnt lgkmcnt(0)" ::: "memory");
#pragma unroll
      for (int jj = 0; jj < 16; jj++) {
        u32 hi = key[jj] >> 8;
        u32 add = (hi == p1.x ? 1u : 0u) + (hi == p2.x ? 0x10000u : 0u);
        if (add) atomicAdd(&hcopy[key[jj] & 255u], add);
      }
      asm volatile("s_waitcnt lgkmcnt(0)" ::: "memory");

      do_scan();
      uint2 q1 = crossx(p1.y, 0);
      uint2 q2 = crossx(p2.y, 16);
      u32 t1u = (p1.x << 8) | q1.x;
      u32 t2u = (p2.x << 8) | q2.x;

      // softmax numerators + masked partition sums
      float ev[16];
      float z1 = 0.f, z2 = 0.f;
#pragma unroll
      for (int jj = 0; jj < 16; jj++) {
        u16 s = (u16)(wd[jj >> 1] >> ((jj & 1) * 16));
        float e = __expf(bf2f(s) - mf);
        ev[jj] = e;
        z1 += (key[jj] >= t1u) ? e : 0.f;
        z2 += (key[jj] >= t2u) ? e : 0.f;
      }
#pragma unroll
      for (int d = 1; d < 64; d <<= 1) {
        z1 += __shfl_xor(z1, d);
        z2 += __shfl_xor(z2, d);
      }
      float c1w = 0.6f / z1, c2w = 0.4f / z2;
      u32 ow[8];
#pragma unroll
      for (int p = 0; p < 8; p++) {
        float s0 = (key[2 * p] >= t1u) ? c1w : 0.f;
        s0 += (key[2 * p] >= t2u) ? c2w : 0.f;
        float s1 = (key[2 * p + 1] >= t1u) ? c1w : 0.f;
        s1 += (key[2 * p + 1] >= t2u) ? c2w : 0.f;
        u32 w0 = __float_as_uint(ev[2 * p] * s0);
        u32 w1 = __float_as_uint(ev[2 * p + 1] * s1);
        ow[p] = (w0 >> 16) | (w1 & 0xffff0000u);
      }
      *(uint4*)&Sb[rr][l * 16] = make_uint4(ow[0], ow[1], ow[2], ow[3]);
      *(uint4*)&Sb[rr][l * 16 + 8] = make_uint4(ow[4], ow[5], ow[6], ow[7]);
    }
  }
  __syncthreads();

  {  // Phase 3: PV, wave w covers context slice [w*256, w*256+256)
    v4f acc[4];
#pragma unroll
    for (int nf = 0; nf < 4; nf++) acc[nf] = (v4f){0.f, 0.f, 0.f, 0.f};
    int cw = w * 256;
    const u16* vbase = &vT[(size_t)(bh * 64) * 1024];
#pragma unroll
    for (int ks = 0; ks < 8; ks++) {
      int c0 = cw + ks * 32;
      v8s a = *(const v8s*)&Sb[lr][c0 + kr * 8];
#pragma unroll
      for (int nf = 0; nf < 4; nf++) {
        v8s bb = *(const v8s*)&vbase[(size_t)(nf * 16 + lr) * 1024 + c0 + kr * 8];
        acc[nf] = MFMA16(a, bb, acc[nf]);
      }
    }
#pragma unroll
    for (int nf = 0; nf < 4; nf++)
#pragma unroll
      for (int j = 0; j < 4; j++) opart[w][kr * 4 + j][nf * 16 + lr] = acc[nf][j];
  }
  __syncthreads();
  {
    int rr = t >> 4, d0 = (t & 15) * 4;
#pragma unroll
    for (int q = 0; q < 4; q++) {
      float v = opart[0][rr][d0 + q] + opart[1][rr][d0 + q] + opart[2][rr][d0 + q] +
                opart[3][rr][d0 + q];
      aobf[(size_t)(b * 1024 + n0 + rr) * 512 + h * 64 + d0 + q] = f2bf(v);
    }
  }
}

// ---------------------------------------------------------------------------
// final: out[b,c,n] = proj_gemm[(b,n),c] + proj_b[c] + x[b,c,n]
__global__ __launch_bounds__(256) void xpose_out(const float* __restrict__ G,
                                                 const float* __restrict__ x,
                                                 const float* __restrict__ pb,
                                                 float* __restrict__ out) {
  __shared__ float T[32][33];
  int blk = blockIdx.x;  // ((b*16 + cb)*32 + nb)
  int nb = blk & 31, cb = (blk >> 5) & 15, b = blk >> 9;
  int c0 = cb * 32, n0 = nb * 32;
  int t = threadIdx.x;
  for (int idx = t; idx < 1024; idx += 256) {
    int nj = idx >> 5, ci = idx & 31;
    T[ci][nj] = G[((size_t)(b * 1024 + n0 + nj)) * 512 + c0 + ci];
  }
  __syncthreads();
  for (int idx = t; idx < 1024; idx += 256) {
    int ci = idx >> 5, nj = idx & 31;
    size_t o = ((size_t)(b * 512 + c0 + ci)) * 1024 + n0 + nj;
    out[o] = T[ci][nj] + pb[c0 + ci] + x[o];
  }
}

// ---------------------------------------------------------------------------
extern "C" void kernel_launch(void* const* d_in, const int* in_sizes, int n_in,
                              void* d_out, int out_size, void* d_ws, size_t ws_size,
                              hipStream_t stream) {
  (void)in_sizes; (void)n_in; (void)out_size; (void)ws_size;
  const float* x = (const float*)d_in[0];
  const float* y = (const float*)d_in[1];
  const float* q_w = (const float*)d_in[2];
  const float* kv_w = (const float*)d_in[3];
  const float* proj_w = (const float*)d_in[4];
  const float* proj_b = (const float*)d_in[5];
  const float* c1w = (const float*)d_in[6];
  const float* c1b = (const float*)d_in[7];
  const float* c2w = (const float*)d_in[8];
  const float* c2b = (const float*)d_in[9];
  const float* c3w = (const float*)d_in[10];
  const float* c3b = (const float*)d_in[11];
  const float* ln_w = (const float*)d_in[12];
  const float* ln_b = (const float*)d_in[13];
  const float* kr1 = (const float*)d_in[14];
  const float* kr2 = (const float*)d_in[15];

  char* p = (char*)d_ws;
  auto alloc = [&](size_t bytes) {
    char* q = p;
    p += (bytes + 255) & ~(size_t)255;
    return q;
  };
  float* yf = (float*)alloc(8ull * 512 * 1024 * 4);      // 16 MB [B,C,N]
  u16* ynbf = (u16*)alloc(8192ull * 512 * 2);            // 8 MB  [B*N, C]
  u16* xsbf = (u16*)alloc(8192ull * 512 * 2);            // 8 MB  [B*N, C]
  u16* qwb = (u16*)alloc(512ull * 512 * 2);
  u16* kvwb = (u16*)alloc(1024ull * 512 * 2);
  u16* pwb = (u16*)alloc(512ull * 512 * 2);
  u16* qbf = (u16*)alloc(8192ull * 512 * 2);             // 8 MB
  u16* kvbf = (u16*)alloc(8192ull * 1024 * 2);           // 16 MB
  u16* vTb = (u16*)alloc(8ull * 8 * 64 * 1024 * 2);      // 8 MB [B,H,64,N]
  u16* aobf = (u16*)alloc(8192ull * 512 * 2);            // 8 MB
  float* projf = (float*)alloc(8192ull * 512 * 4);       // 16 MB

  cvt3<<<1024, 256, 0, stream>>>(q_w, qwb, 512 * 512, kv_w, kvwb, 1024 * 512, proj_w, pwb,
                                 512 * 512);
  conv_kernel<<<8 * 512, 256, 0, stream>>>(y, c1w, c1b, c2w, c2b, c3w, c3b, yf);
  ln_kernel<<<512, 256, 0, stream>>>(yf, ln_w, ln_b, ynbf);
  xpose_x<<<8 * 16 * 32, 256, 0, stream>>>(x, xsbf);
  gemm_nt64<<<64 * 8, 256, 0, stream>>>(xsbf, qwb, qbf, 8192, 512, 512, 1);
  gemm_nt64<<<64 * 16, 256, 0, stream>>>(ynbf, kvwb, kvbf, 8192, 1024, 512, 1);
  xpose_v<<<64 * 16, 256, 0, stream>>>(kvbf, vTb);
  attn_kernel<<<64 * 64, 256, 0, stream>>>(qbf, kvbf, vTb, aobf, kr1, kr2);
  gemm_nt64<<<64 * 8, 256, 0, stream>>>(aobf, pwb, projf, 8192, 512, 512, 0);
  xpose_out<<<8 * 16 * 32, 256, 0, stream>>>(projf, x, proj_b, (float*)d_out);
}